// Round 1
// baseline (319.250 us; speedup 1.0000x reference)
//
#include <hip/hip_runtime.h>
#include <cstdint>
#include <cstddef>

using bf16x8 = __attribute__((ext_vector_type(8))) short;
using f32x4  = __attribute__((ext_vector_type(4))) float;

__device__ __forceinline__ unsigned short f2bf(float f) {
  unsigned int u = __builtin_bit_cast(unsigned int, f);
  u += 0x7FFFu + ((u >> 16) & 1u);   // round-to-nearest-even
  return (unsigned short)(u >> 16);
}
__device__ __forceinline__ float bf2f(unsigned int h16) {
  unsigned int u = h16 << 16;
  return __builtin_bit_cast(float, u);
}

__device__ __forceinline__ void gl_lds16(const void* g, void* l) {
  __builtin_amdgcn_global_load_lds(
      (const __attribute__((address_space(1))) unsigned int*)g,
      (__attribute__((address_space(3))) unsigned int*)l,
      16, 0, 0);
}

#define MFMA __builtin_amdgcn_mfma_f32_16x16x32_bf16

// C[m,n] = sum_k A[m,k]*B[n,k]  (A: MxK, B: NxK, bf16 row-major)
// BK=64, 2-stage LDS double-buffer, raw s_barrier + manual vmcnt.
// LDS chunk map: row r, LDS chunk q holds global chunk q^(r&7).
// Only MODE 2 (bf16 store of c) is instantiated now; used for the two
// small 512-K GEMMs (values and v2T) that feed the fused kernel.
template<int MODE, int SWZ, int WM, int WN>
__global__ __launch_bounds__(WM* WN * 64)
void gemm_bt(const unsigned short* __restrict__ A,
             const unsigned short* __restrict__ B,
             void* __restrict__ Cv,
             int M, int N, int K, int KC,
             const float* __restrict__ aux0,
             const float* __restrict__ aux1,
             const float* __restrict__ aux2,
             float* __restrict__ aux3)
{
  constexpr int THREADS = WM * WN * 64;
  constexpr int BMt = WM * 64, BNt = WN * 64;
  constexpr int NA = BMt * 8 / THREADS;
  constexpr int NB = BNt * 8 / THREADS;
  constexpr int L  = NA + NB;
  constexpr int ASZ = BMt * 64, BSZ = BNt * 64;

  __shared__ unsigned short smem[2 * (ASZ + BSZ)];
  unsigned short* As = smem;
  unsigned short* Bs = smem + 2 * ASZ;

  const int tid  = threadIdx.x;
  const int lane = tid & 63;
  const int wv   = tid >> 6;
  const int wm   = (wv / WN) * 64;
  const int wn   = (wv % WN) * 64;
  const int l16  = lane & 15;
  const int quad = lane >> 4;

  int xt, yt, zt;
  if (SWZ == 0) {
    xt = blockIdx.x; yt = blockIdx.y; zt = 0;
  } else if (SWZ == 1) {
    const int lin = blockIdx.x;
    const int xcd = lin & 7, per = lin >> 3;
    xt = xcd * 4 + (per & 3); yt = per >> 2; zt = 0;
  } else {
    const int lin = blockIdx.x;
    const int xcd = lin & 7, i = lin >> 3;
    yt = xcd * 8 + (i & 7);
    const int combo = i >> 3;
    xt = combo & 3;
    zt = combo >> 2;
  }

  const int n0 = xt * BNt;
  const int m0 = yt * BMt;
  const int kbeg = zt * KC;

  f32x4 acc[4][4];
#pragma unroll
  for (int i = 0; i < 4; ++i)
#pragma unroll
    for (int j = 0; j < 4; ++j) {
      f32x4 z = {0.f, 0.f, 0.f, 0.f};
      acc[i][j] = z;
    }

  const unsigned short* gA[NA]; int lA[NA];
  const unsigned short* gB[NB]; int lB[NB];
#pragma unroll
  for (int i = 0; i < NA; ++i) {
    const int c = tid + i * THREADS;
    const int row = c >> 3, col = ((c & 7) ^ (row & 7)) * 8;
    gA[i] = A + (size_t)(m0 + row) * K + col + kbeg;
    lA[i] = c * 8;
  }
#pragma unroll
  for (int i = 0; i < NB; ++i) {
    const int c = tid + i * THREADS;
    const int row = c >> 3, col = ((c & 7) ^ (row & 7)) * 8;
    gB[i] = B + (size_t)(n0 + row) * K + col + kbeg;
    lB[i] = c * 8;
  }

  auto issue = [&](int st, int kc) {
#pragma unroll
    for (int i = 0; i < NA; ++i) gl_lds16(gA[i] + kc, &As[st * ASZ + lA[i]]);
#pragma unroll
    for (int i = 0; i < NB; ++i) gl_lds16(gB[i] + kc, &Bs[st * BSZ + lB[i]]);
  };

  const int nk = KC >> 6;
  issue(0, 0);

  int cur = 0;
  for (int it = 0; it < nk; ++it) {
    __builtin_amdgcn_s_barrier();
    if (it + 1 < nk) {
      issue(cur ^ 1, (it + 1) << 6);
      __builtin_amdgcn_s_waitcnt(0x0F70 | L);
    } else {
      __builtin_amdgcn_s_waitcnt(0x0F70);
    }
    __builtin_amdgcn_s_barrier();

#pragma unroll
    for (int ks = 0; ks < 2; ++ks) {
      bf16x8 af[4], bfr[4];
#pragma unroll
      for (int mi = 0; mi < 4; ++mi) {
        const int r = wm + mi * 16 + l16;
        af[mi] = *(const bf16x8*)&As[cur * ASZ + r * 64 + (((ks * 4 + quad) ^ (r & 7)) * 8)];
      }
#pragma unroll
      for (int ni = 0; ni < 4; ++ni) {
        const int r = wn + ni * 16 + l16;
        bfr[ni] = *(const bf16x8*)&Bs[cur * BSZ + r * 64 + (((ks * 4 + quad) ^ (r & 7)) * 8)];
      }
#pragma unroll
      for (int mi = 0; mi < 4; ++mi)
#pragma unroll
        for (int ni = 0; ni < 4; ++ni)
          acc[mi][ni] = MFMA(af[mi], bfr[ni], acc[mi][ni], 0, 0, 0);
    }
    cur ^= 1;
  }

  {
    unsigned short* Pz = (unsigned short*)Cv;
    if (MODE == 3) Pz += (size_t)zt * (size_t)M * N;
#pragma unroll
    for (int mi = 0; mi < 4; ++mi) {
#pragma unroll
      for (int r = 0; r < 4; ++r) {
        const int m = m0 + wm + mi * 16 + quad * 4 + r;
#pragma unroll
        for (int ni = 0; ni < 4; ++ni) {
          const int n = n0 + wn + ni * 16 + l16;
          Pz[(size_t)m * N + n] = f2bf(acc[mi][ni][r]);
        }
      }
    }
  }
  (void)aux0; (void)aux1; (void)aux2; (void)aux3;
}

// ================= fused flash-style attention =================
// Per block: 128 x-rows (m-tile), one 1024-neuron n-chunk (split), full e=512.
// nt loop (4 x 256 neurons):
//   phase A: cross[128x256] = x . p^T over K=512 (BK=64 dbuf staging, proven loop)
//   epilogue: E = exp(scale/(dist+0.1)) -> swizzled LDS E-tile; denom atomics
//   phase B: acc[128x512] += E . v2T^T over K=256 in 8 k-quarters; v2T quarter
//            (512x32) double-buffered through the SAME two stage slots.
// All stray vmem (aux loads, atomics) confined to the epilogue and drained
// (vm0+lgkm0) before phase B so counted vmcnt in phase B stays exact.
// LDS: 2 x 48KB stage slots + 64KB E-tile = 160KB exactly -> 1 block/CU, 8 waves.
__global__ __launch_bounds__(512, 2)
void fused_attn(const unsigned short* __restrict__ Xb,   // [8192][512] bf16
                const unsigned short* __restrict__ Pb,   // [4096][512] bf16
                const unsigned short* __restrict__ V2T,  // [512][4096] bf16
                const float* __restrict__ x2g,           // [8192]
                const float* __restrict__ p2g,           // [4096]
                const float* __restrict__ scg,           // [4096]
                float* __restrict__ denom,               // [8192], pre-zeroed
                float* __restrict__ Pout)                // [4][8192][512] f32
{
  constexpr int D = 512, N = 4096, ED = 512, M = 8192;
  constexpr int SLOT = 24576;                 // shorts: A 8192 + B 16384 (48 KB)
  __shared__ unsigned short smem[2 * SLOT + 32768];   // + EB 128x256 = 160 KB
  unsigned short* EB = smem + 2 * SLOT;

  const int tid  = threadIdx.x;
  const int lane = tid & 63;
  const int wv   = tid >> 6;
  const int l16  = lane & 15;
  const int quad = lane >> 4;
  const int wm   = (wv >> 2) * 64;    // phase A/B m-base
  const int wnA  = (wv & 3) * 64;     // phase A n-base (wave tile 64x64)
  const int we   = (wv & 3) * 128;    // phase B e-base (wave tile 64x128)

  // 256 blocks: XCD owns 8 consecutive m-tiles; 4 n-split siblings co-XCD.
  const int lin   = blockIdx.x;
  const int mt    = (lin & 7) * 8 + ((lin >> 3) & 7);
  const int split = lin >> 6;
  const int m0  = mt * 128;
  const int nch = split * 1024;

  // staging addresses (chunk q of row r holds global chunk q^(r&7))
  const unsigned short* gA[2]; int lA[2];
  const unsigned short* gB[4]; int lB[4];
#pragma unroll
  for (int i = 0; i < 2; ++i) {
    const int c = tid + i * 512;
    const int row = c >> 3, col = ((c & 7) ^ (row & 7)) * 8;
    gA[i] = Xb + (size_t)(m0 + row) * D + col;
    lA[i] = c * 8;
  }
#pragma unroll
  for (int i = 0; i < 4; ++i) {
    const int c = tid + i * 512;
    const int row = c >> 3, col = ((c & 7) ^ (row & 7)) * 8;
    gB[i] = Pb + (size_t)(nch + row) * D + col;
    lB[i] = c * 8;
  }
  // v2T slot: 512 rows x 32 cols; pos p of row r holds global chunk p^((r>>1)&3)
  const unsigned short* gV = V2T + (size_t)(tid >> 2) * N
                             + (((tid & 3) ^ ((tid >> 3) & 3)) * 8) + nch;
  const int lV = tid * 8;

  auto issueA = [&](int st, int nt, int kc) {          // 6 loads/thread
    unsigned short* S = smem + st * SLOT;
    const int boff = nt * 131072;                      // 256 rows * 512
#pragma unroll
    for (int i = 0; i < 2; ++i) gl_lds16(gA[i] + kc, &S[lA[i]]);
#pragma unroll
    for (int i = 0; i < 4; ++i) gl_lds16(gB[i] + boff + kc, &S[8192 + lB[i]]);
  };
  auto issueV = [&](int st, int ncol) {                // 4 loads/thread
    unsigned short* S = smem + st * SLOT;
#pragma unroll
    for (int i = 0; i < 4; ++i)
      gl_lds16(gV + (size_t)i * 524288 + ncol, &S[lV + i * 4096]);
  };

  f32x4 acc[4][8];
#pragma unroll
  for (int i = 0; i < 4; ++i)
#pragma unroll
    for (int j = 0; j < 8; ++j) {
      f32x4 z = {0.f, 0.f, 0.f, 0.f};
      acc[i][j] = z;
    }

  issueA(0, 0, 0);

  for (int nt = 0; nt < 4; ++nt) {
    f32x4 cacc[4][4];
#pragma unroll
    for (int i = 0; i < 4; ++i)
#pragma unroll
      for (int j = 0; j < 4; ++j) {
        f32x4 z = {0.f, 0.f, 0.f, 0.f};
        cacc[i][j] = z;
      }

    // ---- phase A: cross GEMM, 8 BK=64 steps ----
    int cur = 0;
    for (int it = 0; it < 8; ++it) {
      __builtin_amdgcn_s_barrier();
      if (it < 7) {
        issueA(cur ^ 1, nt, (it + 1) << 6);
        __builtin_amdgcn_s_waitcnt(0x0F76);   // my 6 landed; next 6 in flight
      } else {
        issueV(cur ^ 1, nt * 256);            // prefetch v2T q0 under epilogue
        __builtin_amdgcn_s_waitcnt(0x0F74);   // my 6 landed; 4 V in flight
      }
      __builtin_amdgcn_s_barrier();
      const unsigned short* As = smem + cur * SLOT;
      const unsigned short* Bs = As + 8192;
#pragma unroll
      for (int ks = 0; ks < 2; ++ks) {
        bf16x8 af[4], bfq[4];
#pragma unroll
        for (int mi = 0; mi < 4; ++mi) {
          const int r = wm + mi * 16 + l16;
          af[mi] = *(const bf16x8*)&As[r * 64 + (((ks * 4 + quad) ^ (r & 7)) * 8)];
        }
#pragma unroll
        for (int ni = 0; ni < 4; ++ni) {
          const int r = wnA + ni * 16 + l16;
          bfq[ni] = *(const bf16x8*)&Bs[r * 64 + (((ks * 4 + quad) ^ (r & 7)) * 8)];
        }
#pragma unroll
        for (int mi = 0; mi < 4; ++mi)
#pragma unroll
          for (int ni = 0; ni < 4; ++ni)
            cacc[mi][ni] = MFMA(af[mi], bfq[ni], cacc[mi][ni], 0, 0, 0);
      }
      cur ^= 1;
    }
    // after loop: cur==0; v2T q0 in-flight into slot 0

    // ---- epilogue A: E = exp(scale/(dist+0.1)), EB store, denom atomics ----
    {
      float p2v[4], scv[4];
#pragma unroll
      for (int ni = 0; ni < 4; ++ni) {
        const int n = nch + nt * 256 + wnA + ni * 16 + l16;
        p2v[ni] = p2g[n];
        scv[ni] = scg[n] * 1.44269504088896f;   // fold log2(e)
      }
#pragma unroll
      for (int mi = 0; mi < 4; ++mi) {
#pragma unroll
        for (int r4 = 0; r4 < 4; ++r4) {
          const int rowL = wm + mi * 16 + quad * 4 + r4;
          const float rowa = x2g[m0 + rowL];
          float s = 0.f;
#pragma unroll
          for (int ni = 0; ni < 4; ++ni) {
            const int col = wnA + ni * 16 + l16;
            const float v = cacc[mi][ni][r4];
            float sq   = fmaxf(rowa - 2.0f * v + p2v[ni], 0.0f);
            float dist = __builtin_amdgcn_sqrtf(sq);
            float e    = __builtin_amdgcn_exp2f(scv[ni] * __builtin_amdgcn_rcpf(dist + 0.1f));
            EB[rowL * 256 + (((col >> 3) ^ (rowL & 7)) * 8) + (col & 7)] = f2bf(e);
            s += e;
          }
          s += __shfl_down(s, 8);
          s += __shfl_down(s, 4);
          s += __shfl_down(s, 2);
          s += __shfl_down(s, 1);
          if (l16 == 0) unsafeAtomicAdd(&denom[m0 + rowL], s);
        }
      }
    }
    // drain EB stores (lgkm), v2T q0, aux loads, atomics: phase-B vmcnt exact
    __builtin_amdgcn_s_waitcnt(0x0070);

    // ---- phase B: acc += E . v2T^T, 8 k-quarters of 32 ----
#pragma unroll
    for (int q = 0; q < 8; ++q) {
      __builtin_amdgcn_s_barrier();           // prev readers done with slot (q+1)&1
      if (q < 7) {
        issueV((q + 1) & 1, nt * 256 + (q + 1) * 32);
        __builtin_amdgcn_s_waitcnt(0x0F74);   // quarter q landed
      } else if (nt < 3) {
        issueA(0, nt + 1, 0);                 // prefetch next tile's phase A
        __builtin_amdgcn_s_waitcnt(0x0F76);   // q7 landed; 6 A in flight
      } else {
        __builtin_amdgcn_s_waitcnt(0x0F70);
      }
      __builtin_amdgcn_s_barrier();           // everyone's quarter visible
      const unsigned short* Vs = smem + (q & 1) * SLOT;
      bf16x8 afE[4], bfV[8];
#pragma unroll
      for (int mi = 0; mi < 4; ++mi) {
        const int r = wm + mi * 16 + l16;
        afE[mi] = *(const bf16x8*)&EB[r * 256 + (((q * 4 + quad) ^ (r & 7)) * 8)];
      }
#pragma unroll
      for (int ei = 0; ei < 8; ++ei) {
        const int er = we + ei * 16 + l16;
        bfV[ei] = *(const bf16x8*)&Vs[er * 32 + ((quad ^ ((er >> 1) & 3)) * 8)];
      }
#pragma unroll
      for (int mi = 0; mi < 4; ++mi)
#pragma unroll
        for (int ei = 0; ei < 8; ++ei)
          acc[mi][ei] = MFMA(afE[mi], bfV[ei], acc[mi][ei], 0, 0, 0);
    }
  }

  // ---- final store: fp32 partial, one per n-split ----
  float* P = Pout + (size_t)split * ((size_t)M * ED);
#pragma unroll
  for (int mi = 0; mi < 4; ++mi)
#pragma unroll
    for (int r4 = 0; r4 < 4; ++r4) {
      const int m = m0 + wm + mi * 16 + quad * 4 + r4;
#pragma unroll
      for (int ei = 0; ei < 8; ++ei)
        P[(size_t)m * ED + we + ei * 16 + l16] = acc[mi][ei][r4];
    }
}

// ===== prep_all: all conversions/norms/bias in ONE launch (3456 blocks) =====
__global__ void prep_all(const float* __restrict__ x, const float* __restrict__ positions,
                         const float* __restrict__ w_v, const float* __restrict__ w_o,
                         const float* __restrict__ b_v, const float* __restrict__ b_o,
                         unsigned short* __restrict__ xb, unsigned short* __restrict__ pb,
                         unsigned short* __restrict__ wvb, unsigned short* __restrict__ wob,
                         float* __restrict__ x2, float* __restrict__ p2,
                         float* __restrict__ bias2, float* __restrict__ denom)
{
  const int b = blockIdx.x;
  const int tid = threadIdx.x;
  const int lane = tid & 63;
  const int wv = tid >> 6;

  if (b < 3072) {
    const bool isx = (b < 2048);
    const int r = (isx ? b : b - 2048) * 4 + wv;
    const float* X = isx ? x : positions;
    unsigned short* Xb = isx ? xb : pb;
    const float4* row = (const float4*)(X + (size_t)r * 512);
    const float4 a = row[lane];
    const float4 c = row[lane + 64];
    ushort4 ua, uc;
    ua.x = f2bf(a.x); ua.y = f2bf(a.y); ua.z = f2bf(a.z); ua.w = f2bf(a.w);
    uc.x = f2bf(c.x); uc.y = f2bf(c.y); uc.z = f2bf(c.z); uc.w = f2bf(c.w);
    ushort4* orow = (ushort4*)(Xb + (size_t)r * 512);
    orow[lane] = ua;
    orow[lane + 64] = uc;
    float s = a.x*a.x + a.y*a.y + a.z*a.z + a.w*a.w
            + c.x*c.x + c.y*c.y + c.z*c.z + c.w*c.w;
#pragma unroll
    for (int off = 32; off > 0; off >>= 1) s += __shfl_down(s, off, 64);
    if (lane == 0) {
      if (isx) { x2[r] = s; denom[r] = 0.f; }
      else     { p2[r] = s; }
    }
  } else if (b < 3328) {
    const int i = (b - 3072) * 256 + tid;
    float4 a = ((const float4*)w_v)[i];
    float4 c = ((const float4*)w_o)[i];
    ushort4 ua, uc;
    ua.x = f2bf(a.x); ua.y = f2bf(a.y); ua.z = f2bf(a.z); ua.w = f2bf(a.w);
    uc.x = f2bf(c.x); uc.y = f2bf(c.y); uc.z = f2bf(c.z); uc.w = f2bf(c.w);
    ((ushort4*)wvb)[i] = ua;
    ((ushort4*)wob)[i] = uc;
  } else {
    const int e = (b - 3328) * 4 + wv;
    float s = 0.f;
#pragma unroll
    for (int j = 0; j < 8; ++j)
      s += w_o[(size_t)e * 512 + lane + j * 64] * b_v[lane + j * 64];
#pragma unroll
    for (int off = 32; off > 0; off >>= 1) s += __shfl_down(s, off, 64);
    if (lane == 0) bias2[e] = b_o[e] + s;   // softmax rows sum to 1
  }
}

// out[m,e] = (P0+P1+P2+P3)[m,e]/denom[m] + bias2[e]   (P fp32 partials)
__global__ void reduce_out4(const float* __restrict__ P,
                            const float* __restrict__ denom,
                            const float* __restrict__ bias2,
                            float* __restrict__ out) {
  const int i = blockIdx.x * 256 + threadIdx.x;   // 1,048,576 float4s
  const int m = i >> 7;
  const float rd = 1.0f / denom[m];
  const float4 b4 = ((const float4*)bias2)[i & 127];
  const float4* PP = (const float4*)P;
  const float4 a = PP[i];
  const float4 b = PP[i + 1048576];
  const float4 c = PP[i + 2097152];
  const float4 d = PP[i + 3145728];
  float4 o;
  o.x = (a.x + b.x + c.x + d.x) * rd + b4.x;
  o.y = (a.y + b.y + c.y + d.y) * rd + b4.y;
  o.z = (a.z + b.z + c.z + d.z) * rd + b4.z;
  o.w = (a.w + b.w + c.w + d.w) * rd + b4.w;
  ((float4*)out)[i] = o;
}

extern "C" void kernel_launch(void* const* d_in, const int* in_sizes, int n_in,
                              void* d_out, int out_size, void* d_ws, size_t ws_size,
                              hipStream_t stream) {
  const float* x         = (const float*)d_in[0];
  const float* positions = (const float*)d_in[1];
  const float* scale     = (const float*)d_in[2];
  const float* w_v       = (const float*)d_in[3];
  const float* b_v       = (const float*)d_in[4];
  const float* w_o       = (const float*)d_in[5];
  const float* b_o       = (const float*)d_in[6];
  float* out = (float*)d_out;

  char* base = (char*)d_ws;
  float*          P4    = (float*)(base + 0);                 // 64 MB fp32 partials
  unsigned short* val   = (unsigned short*)(base + 0);        // 4 MB, parks in P4
  unsigned short* v2T   = (unsigned short*)(base + 67108864); // 4 MB
  float*          denom = (float*)(base + 71303168);          // 32 KB
  float*          x2    = (float*)(base + 71335936);          // 32 KB
  float*          p2    = (float*)(base + 71368704);          // 16 KB
  float*          bias2 = (float*)(base + 71385088);          // 2 KB
  unsigned short* xb    = (unsigned short*)(base + 71387136); // 8 MB
  unsigned short* pb    = (unsigned short*)(base + 79775744); // 4 MB
  unsigned short* wvb   = (unsigned short*)(base + 83970048); // 0.5 MB
  unsigned short* wo_b  = (unsigned short*)(base + 84494336); // 0.5 MB

  // all prep in one launch
  prep_all<<<3456, 256, 0, stream>>>(x, positions, w_v, w_o, b_v, b_o,
                                     xb, pb, wvb, wo_b, x2, p2, bias2, denom);

  // val[n,d] = sum_k p[n,k] wv[d,k]
  gemm_bt<2, 0, 2, 2><<<dim3(4, 32), 256, 0, stream>>>(
      pb, wvb, val, 4096, 512, 512, 512, nullptr, nullptr, nullptr, nullptr);

  // v2T[e,n] = sum_d wo[e,d] val[n,d]
  gemm_bt<2, 0, 2, 2><<<dim3(32, 4), 256, 0, stream>>>(
      wo_b, val, v2T, 512, 4096, 512, 512, nullptr, nullptr, nullptr, nullptr);

  // fused: E-tile GEMM + exp + PV GEMM, fp32 partials + denom atomics
  fused_attn<<<256, 512, 0, stream>>>(xb, pb, v2T, x2, p2, scale, denom, P4);

  // out = (P0+P1+P2+P3)/denom + bias2
  reduce_out4<<<4096, 256, 0, stream>>>(P4, denom, bias2, out);
}

// Round 2
// 236.468 us; speedup vs baseline: 1.3501x; 1.3501x over previous
//
#include <hip/hip_runtime.h>
#include <cstdint>
#include <cstddef>

using bf16x8 = __attribute__((ext_vector_type(8))) short;
using f32x4  = __attribute__((ext_vector_type(4))) float;

__device__ __forceinline__ unsigned short f2bf(float f) {
  unsigned int u = __builtin_bit_cast(unsigned int, f);
  u += 0x7FFFu + ((u >> 16) & 1u);   // round-to-nearest-even
  return (unsigned short)(u >> 16);
}
__device__ __forceinline__ float bf2f(unsigned int h16) {
  unsigned int u = h16 << 16;
  return __builtin_bit_cast(float, u);
}

#define MFMA __builtin_amdgcn_mfma_f32_16x16x32_bf16

// C[m,n] = sum_{k in z-slice} A[m,k]*B[n,k]  (A: MxK, B: NxK, bf16 row-major)
// BK=64, 2-slot LDS double-buffer fed by DISTANCE-2 REGISTER STAGING:
//   iter it: issue global->reg batch(it+2); vmcnt(8) waits batch(it+1) only
//   (batch it+2 stays in flight across both barriers); ds_write batch(it+1)
//   to slot[(it+1)&1]; lgkm0; barrier; ds_read slot[it&1] + 32 MFMA; barrier.
// Round-0 used global_load_lds at distance 1: the vmcnt stall (~1.1Kcy/iter,
// staging latency > per-iter compute) dominated (MfmaUtil 15%). Distance-2
// gives loads ~2 iters (~1.4Kcy) to land. Reg sets are ping-ponged with
// static names (rule #20: no runtime-indexed reg arrays); nk is even at all
// call sites so a 2x-unrolled loop keeps every index a literal.
// LDS chunk map: row r, LDS chunk q holds global chunk q^(r&7)  (b128 reads
// 2-way bank aliased = free).
// MODE 0: E=exp(scale[n]/(dist+0.1)) -> LDS-transpose coalesced store; row sums atomic
// MODE 2: bf16 store of c
// MODE 3: bf16 store of c into partial slice z
// SWZ 0: plain 2-D grid. SWZ 1: 2048 1-D, XCD owns 4-wide n-band.
// SWZ 4: 512 1-D, XCD owns 8 m-tiles x 8 (e,z); E-slices L2-resident.
template<int MODE, int SWZ, int WM, int WN>
__global__ __launch_bounds__(WM* WN * 64)
void gemm_bt(const unsigned short* __restrict__ A,
             const unsigned short* __restrict__ B,
             void* __restrict__ Cv,
             int M, int N, int K, int KC,
             const float* __restrict__ aux0,
             const float* __restrict__ aux1,
             const float* __restrict__ aux2,
             float* __restrict__ aux3)
{
  constexpr int THREADS = WM * WN * 64;
  constexpr int BMt = WM * 64, BNt = WN * 64;
  constexpr int NA = BMt * 8 / THREADS;   // A 16B-chunks per thread per stage
  constexpr int NB = BNt * 8 / THREADS;
  constexpr int L  = NA + NB;
  static_assert(L <= 15, "vmcnt low-bits encoding");
  constexpr int ASZ = BMt * 64, BSZ = BNt * 64;   // shorts per stage

  __shared__ unsigned short smem[2 * (ASZ + BSZ)];
  unsigned short* As = smem;
  unsigned short* Bs = smem + 2 * ASZ;

  const int tid  = threadIdx.x;
  const int lane = tid & 63;
  const int wv   = tid >> 6;
  const int wm   = (wv / WN) * 64;
  const int wn   = (wv % WN) * 64;
  const int l16  = lane & 15;
  const int quad = lane >> 4;

  int xt, yt, zt;
  if (SWZ == 0) {
    xt = blockIdx.x; yt = blockIdx.y; zt = 0;
  } else if (SWZ == 1) {
    const int lin = blockIdx.x;
    const int xcd = lin & 7, per = lin >> 3;
    xt = xcd * 4 + (per & 3); yt = per >> 2; zt = 0;
  } else {                                  // SWZ 4
    const int lin = blockIdx.x;             // 512 blocks
    const int xcd = lin & 7, i = lin >> 3;  // i in [0,64)
    yt = xcd * 8 + (i & 7);                 // m-tile octet pinned to XCD
    const int combo = i >> 3;               // 0..7
    xt = combo & 3;                         // e-tile
    zt = combo >> 2;                        // K half
  }

  const int n0 = xt * BNt;
  const int m0 = yt * BMt;
  const int kbeg = zt * KC;

  f32x4 acc[4][4];
#pragma unroll
  for (int i = 0; i < 4; ++i)
#pragma unroll
    for (int j = 0; j < 4; ++j) {
      f32x4 z = {0.f, 0.f, 0.f, 0.f};
      acc[i][j] = z;
    }

  // staging: LDS chunk c holds global chunk (c&7)^((c>>3)&7) of row c>>3
  const unsigned short* gA[NA]; int lA[NA];
  const unsigned short* gB[NB]; int lB[NB];
#pragma unroll
  for (int i = 0; i < NA; ++i) {
    const int c = tid + i * THREADS;
    const int row = c >> 3, col = ((c & 7) ^ (row & 7)) * 8;
    gA[i] = A + (size_t)(m0 + row) * K + col + kbeg;
    lA[i] = c * 8;
  }
#pragma unroll
  for (int i = 0; i < NB; ++i) {
    const int c = tid + i * THREADS;
    const int row = c >> 3, col = ((c & 7) ^ (row & 7)) * 8;
    gB[i] = B + (size_t)(n0 + row) * K + col + kbeg;
    lB[i] = c * 8;
  }

  // distance-2 register staging: two named sets (even/odd batches)
  bf16x8 rAe[NA], rBe[NB], rAo[NA], rBo[NB];

  auto loadE = [&](int kc) {
#pragma unroll
    for (int i = 0; i < NA; ++i) rAe[i] = *(const bf16x8*)(gA[i] + kc);
#pragma unroll
    for (int i = 0; i < NB; ++i) rBe[i] = *(const bf16x8*)(gB[i] + kc);
  };
  auto loadO = [&](int kc) {
#pragma unroll
    for (int i = 0; i < NA; ++i) rAo[i] = *(const bf16x8*)(gA[i] + kc);
#pragma unroll
    for (int i = 0; i < NB; ++i) rBo[i] = *(const bf16x8*)(gB[i] + kc);
  };
  auto writeE = [&](int st) {
#pragma unroll
    for (int i = 0; i < NA; ++i) *(bf16x8*)&As[st * ASZ + lA[i]] = rAe[i];
#pragma unroll
    for (int i = 0; i < NB; ++i) *(bf16x8*)&Bs[st * BSZ + lB[i]] = rBe[i];
  };
  auto writeO = [&](int st) {
#pragma unroll
    for (int i = 0; i < NA; ++i) *(bf16x8*)&As[st * ASZ + lA[i]] = rAo[i];
#pragma unroll
    for (int i = 0; i < NB; ++i) *(bf16x8*)&Bs[st * BSZ + lB[i]] = rBo[i];
  };
  auto compute = [&](int st) {
#pragma unroll
    for (int ks = 0; ks < 2; ++ks) {
      bf16x8 af[4], bfr[4];
#pragma unroll
      for (int mi = 0; mi < 4; ++mi) {
        const int r = wm + mi * 16 + l16;
        af[mi] = *(const bf16x8*)&As[st * ASZ + r * 64 + (((ks * 4 + quad) ^ (r & 7)) * 8)];
      }
#pragma unroll
      for (int ni = 0; ni < 4; ++ni) {
        const int r = wn + ni * 16 + l16;
        bfr[ni] = *(const bf16x8*)&Bs[st * BSZ + r * 64 + (((ks * 4 + quad) ^ (r & 7)) * 8)];
      }
#pragma unroll
      for (int mi = 0; mi < 4; ++mi)
#pragma unroll
        for (int ni = 0; ni < 4; ++ni)
          acc[mi][ni] = MFMA(af[mi], bfr[ni], acc[mi][ni], 0, 0, 0);
    }
  };

  const int nk = KC >> 6;   // BK = 64; even at all call sites (8 or 32)

  // ---- prologue: batches 0,1 in flight; slot0 <- batch0 ----
  loadE(0);
  loadO(1 << 6);
  __builtin_amdgcn_s_waitcnt(0x0F70 | L);   // batch0 landed (batch1 flying)
  writeE(0);
  __builtin_amdgcn_s_waitcnt(0x0070);       // my ds_writes drained
  __builtin_amdgcn_s_barrier();             // slot0 visible to all

  for (int it = 0; it < nk; it += 2) {
    // ---- even iter: compute slot0; write batch(it+1)->slot1; issue batch(it+2)
    if (it + 2 < nk) loadE((it + 2) << 6);
    {
      if (it + 2 < nk) __builtin_amdgcn_s_waitcnt(0x0F70 | L);  // batch it+1 landed
      else             __builtin_amdgcn_s_waitcnt(0x0F70);
      writeO(1);
      __builtin_amdgcn_s_waitcnt(0x0070);
    }
    __builtin_amdgcn_s_barrier();           // slot1 visible; slot0 stable
    compute(0);
    __builtin_amdgcn_s_barrier();           // all readers done with slot0
    // ---- odd iter it+1: compute slot1; write batch(it+2)->slot0; issue batch(it+3)
    if (it + 3 < nk) loadO((it + 3) << 6);
    if (it + 2 < nk) {
      if (it + 3 < nk) __builtin_amdgcn_s_waitcnt(0x0F70 | L);  // batch it+2 landed
      else             __builtin_amdgcn_s_waitcnt(0x0F70);
      writeE(0);
      __builtin_amdgcn_s_waitcnt(0x0070);
    }
    __builtin_amdgcn_s_barrier();
    compute(1);
    __builtin_amdgcn_s_barrier();
  }

  // ---- epilogue ----
  if constexpr (MODE == 0) {
    // (only instantiated with WM=WN=2, THREADS=256, BMt=BNt=128)
    float p2v[4], scv[4];
#pragma unroll
    for (int ni = 0; ni < 4; ++ni) {
      const int n = n0 + wn + ni * 16 + l16;
      p2v[ni] = aux1[n];
      scv[ni] = aux2[n] * 1.44269504088896f;   // fold log2(e)
    }
    __syncthreads();                            // done with K-loop LDS
    unsigned short* Es = smem;                  // 128 x (136-stride) bf16 tile
#pragma unroll
    for (int mi = 0; mi < 4; ++mi) {
#pragma unroll
      for (int r = 0; r < 4; ++r) {
        const int rowL = wm + mi * 16 + quad * 4 + r;
        const float rowa = aux0[m0 + rowL];
        float s = 0.f;
#pragma unroll
        for (int ni = 0; ni < 4; ++ni) {
          const int col = wn + ni * 16 + l16;
          const float v = acc[mi][ni][r];
          float sq   = fmaxf(rowa - 2.0f * v + p2v[ni], 0.0f);
          float dist = __builtin_amdgcn_sqrtf(sq);
          float e    = __builtin_amdgcn_exp2f(scv[ni] * __builtin_amdgcn_rcpf(dist + 0.1f));
          Es[rowL * 136 + col] = f2bf(e);
          s += e;                                // unrounded sum (rel err ~3e-5)
        }
        s += __shfl_down(s, 8);
        s += __shfl_down(s, 4);
        s += __shfl_down(s, 2);
        s += __shfl_down(s, 1);
        if (l16 == 0) unsafeAtomicAdd(&aux3[m0 + rowL], s);
      }
    }
    __syncthreads();
    unsigned short* Eg = (unsigned short*)Cv;
#pragma unroll
    for (int j = 0; j < 8; ++j) {               // coalesced 16B stores
      const int cid = j * 256 + tid;
      const int row = cid >> 4, c = cid & 15;
      bf16x8 v = *(const bf16x8*)&Es[row * 136 + c * 8];
      *(bf16x8*)&Eg[(size_t)(m0 + row) * N + n0 + c * 8] = v;
    }
  } else {
    unsigned short* Pz = (unsigned short*)Cv;
    if (MODE == 3) Pz += (size_t)zt * (size_t)M * N;
#pragma unroll
    for (int mi = 0; mi < 4; ++mi) {
#pragma unroll
      for (int r = 0; r < 4; ++r) {
        const int m = m0 + wm + mi * 16 + quad * 4 + r;
#pragma unroll
        for (int ni = 0; ni < 4; ++ni) {
          const int n = n0 + wn + ni * 16 + l16;
          Pz[(size_t)m * N + n] = f2bf(acc[mi][ni][r]);
        }
      }
    }
  }
}

// ===== prep_all: all conversions/norms/bias in ONE launch (3456 blocks) =====
// [0,2048): x rows -> xb,x2,denom=0 ; [2048,3072): p rows -> pb,p2 ;
// [3072,3328): wv,wo -> bf16 (straight) ; [3328,3456): bias2
__global__ void prep_all(const float* __restrict__ x, const float* __restrict__ positions,
                         const float* __restrict__ w_v, const float* __restrict__ w_o,
                         const float* __restrict__ b_v, const float* __restrict__ b_o,
                         unsigned short* __restrict__ xb, unsigned short* __restrict__ pb,
                         unsigned short* __restrict__ wvb, unsigned short* __restrict__ wob,
                         float* __restrict__ x2, float* __restrict__ p2,
                         float* __restrict__ bias2, float* __restrict__ denom)
{
  const int b = blockIdx.x;
  const int tid = threadIdx.x;
  const int lane = tid & 63;
  const int wv = tid >> 6;

  if (b < 3072) {
    const bool isx = (b < 2048);
    const int r = (isx ? b : b - 2048) * 4 + wv;
    const float* X = isx ? x : positions;
    unsigned short* Xb = isx ? xb : pb;
    const float4* row = (const float4*)(X + (size_t)r * 512);
    const float4 a = row[lane];
    const float4 c = row[lane + 64];
    ushort4 ua, uc;
    ua.x = f2bf(a.x); ua.y = f2bf(a.y); ua.z = f2bf(a.z); ua.w = f2bf(a.w);
    uc.x = f2bf(c.x); uc.y = f2bf(c.y); uc.z = f2bf(c.z); uc.w = f2bf(c.w);
    ushort4* orow = (ushort4*)(Xb + (size_t)r * 512);
    orow[lane] = ua;
    orow[lane + 64] = uc;
    float s = a.x*a.x + a.y*a.y + a.z*a.z + a.w*a.w
            + c.x*c.x + c.y*c.y + c.z*c.z + c.w*c.w;
#pragma unroll
    for (int off = 32; off > 0; off >>= 1) s += __shfl_down(s, off, 64);
    if (lane == 0) {
      if (isx) { x2[r] = s; denom[r] = 0.f; }
      else     { p2[r] = s; }
    }
  } else if (b < 3328) {
    const int i = (b - 3072) * 256 + tid;   // 65536 float4 each
    float4 a = ((const float4*)w_v)[i];
    float4 c = ((const float4*)w_o)[i];
    ushort4 ua, uc;
    ua.x = f2bf(a.x); ua.y = f2bf(a.y); ua.z = f2bf(a.z); ua.w = f2bf(a.w);
    uc.x = f2bf(c.x); uc.y = f2bf(c.y); uc.z = f2bf(c.z); uc.w = f2bf(c.w);
    ((ushort4*)wvb)[i] = ua;
    ((ushort4*)wob)[i] = uc;
  } else {
    const int e = (b - 3328) * 4 + wv;
    float s = 0.f;
#pragma unroll
    for (int j = 0; j < 8; ++j)
      s += w_o[(size_t)e * 512 + lane + j * 64] * b_v[lane + j * 64];
#pragma unroll
    for (int off = 32; off > 0; off >>= 1) s += __shfl_down(s, off, 64);
    if (lane == 0) bias2[e] = b_o[e] + s;   // softmax rows sum to 1
  }
}

// out[m,e] = (P0[m,e] + P1[m,e]) / denom[m] + bias2[e]   (P bf16, out fp32)
__global__ void reduce_out(const unsigned short* __restrict__ P,
                           const float* __restrict__ denom,
                           const float* __restrict__ bias2,
                           float* __restrict__ out) {
  const int i = blockIdx.x * 256 + threadIdx.x;   // 1,048,576 float4s
  const int m = i >> 7;
  const float rd = 1.0f / denom[m];
  const float4 b4 = ((const float4*)bias2)[i & 127];
  const ushort4 p0 = ((const ushort4*)P)[i];
  const ushort4 p1 = ((const ushort4*)P)[i + 1048576];
  float4 o;
  o.x = (bf2f(p0.x) + bf2f(p1.x)) * rd + b4.x;
  o.y = (bf2f(p0.y) + bf2f(p1.y)) * rd + b4.y;
  o.z = (bf2f(p0.z) + bf2f(p1.z)) * rd + b4.z;
  o.w = (bf2f(p0.w) + bf2f(p1.w)) * rd + b4.w;
  ((float4*)out)[i] = o;
}

extern "C" void kernel_launch(void* const* d_in, const int* in_sizes, int n_in,
                              void* d_out, int out_size, void* d_ws, size_t ws_size,
                              hipStream_t stream) {
  const float* x         = (const float*)d_in[0];
  const float* positions = (const float*)d_in[1];
  const float* scale     = (const float*)d_in[2];
  const float* w_v       = (const float*)d_in[3];
  const float* b_v       = (const float*)d_in[4];
  const float* w_o       = (const float*)d_in[5];
  const float* b_o       = (const float*)d_in[6];
  float* out = (float*)d_out;

  const int M = 8192, N = 4096, D = 512;

  char* base = (char*)d_ws;
  unsigned short* Eb    = (unsigned short*)(base + 0);          // 64 MB [MODE-0 .. MODE-3]
  unsigned short* val   = (unsigned short*)(base + 0);          // 4 MB, parks in Eb [val-GEMM .. v2T-GEMM]
  unsigned short* v2T   = (unsigned short*)(base + 67108864);   // 4 MB
  float*          denom = (float*)(base + 71303168);            // 32 KB
  float*          x2    = (float*)(base + 71335936);            // 32 KB
  float*          p2    = (float*)(base + 71368704);            // 16 KB
  float*          bias2 = (float*)(base + 71385088);            // 2 KB
  char* base2 = base + 71387136;
  unsigned short* part  = (unsigned short*)base2;               // 16 MB [MODE-3 .. reduce]
  unsigned short* xb    = (unsigned short*)base2;               // 8 MB  [prep .. MODE-0]
  unsigned short* pb    = (unsigned short*)(base2 + 8388608);   // 4 MB  [prep .. MODE-0]
  unsigned short* wvb   = (unsigned short*)(base2 + 12582912);  // 0.5 MB [prep .. val-GEMM]
  unsigned short* wo_b  = (unsigned short*)(base2 + 13107200);  // 0.5 MB [prep .. v2T-GEMM]

  // all prep in one launch
  prep_all<<<3456, 256, 0, stream>>>(x, positions, w_v, w_o, b_v, b_o,
                                     xb, pb, wvb, wo_b, x2, p2, bias2, denom);

  // val[n,d] = sum_k p[n,k] wv[d,k]
  gemm_bt<2, 0, 2, 2><<<dim3(4, 32), 256, 0, stream>>>(
      pb, wvb, val, 4096, 512, 512, 512, nullptr, nullptr, nullptr, nullptr);

  // v2T[e,n] = sum_d wo[e,d] val[n,d]
  gemm_bt<2, 0, 2, 2><<<dim3(32, 4), 256, 0, stream>>>(
      wo_b, val, v2T, 512, 4096, 512, 512, nullptr, nullptr, nullptr, nullptr);

  // E[m,n] = exp(scale[n]/(dist+0.1)); denom[m] += row sums
  gemm_bt<0, 1, 2, 2><<<2048, 256, 0, stream>>>(
      xb, pb, Eb, M, N, D, D, x2, p2, scale, denom);

  // part[z][m,e] = sum_{n in half z} E[m,n] v2T[e,n]
  gemm_bt<3, 4, 2, 2><<<512, 256, 0, stream>>>(
      Eb, v2T, part, M, D, N, N / 2, nullptr, nullptr, nullptr, nullptr);

  // out = (part0 + part1)/denom + bias2
  reduce_out<<<4096, 256, 0, stream>>>(part, denom, bias2, out);
}

// Round 3
// 217.524 us; speedup vs baseline: 1.4677x; 1.0871x over previous
//
#include <hip/hip_runtime.h>
#include <cstdint>
#include <cstddef>

using bf16x8 = __attribute__((ext_vector_type(8))) short;
using f32x4  = __attribute__((ext_vector_type(4))) float;

__device__ __forceinline__ unsigned short f2bf(float f) {
  unsigned int u = __builtin_bit_cast(unsigned int, f);
  u += 0x7FFFu + ((u >> 16) & 1u);   // round-to-nearest-even
  return (unsigned short)(u >> 16);
}
__device__ __forceinline__ float bf2f(unsigned int h16) {
  unsigned int u = h16 << 16;
  return __builtin_bit_cast(float, u);
}

__device__ __forceinline__ void gl_lds16(const void* g, void* l) {
  __builtin_amdgcn_global_load_lds(
      (const __attribute__((address_space(1))) unsigned int*)g,
      (__attribute__((address_space(3))) unsigned int*)l,
      16, 0, 0);
}

#define MFMA __builtin_amdgcn_mfma_f32_16x16x32_bf16

// ================= 256-wide 2-phase GEMM (one barrier per K-step) ========
// C[m,n] = sum_{k in z-slice} A[m,k]*B[n,k]  (A: MxK, B: NxK, bf16 row-major)
// BM=256, BN=64*NI, BK=64, 8 waves (2m x 4n), per-wave tile 128 x 16*NI.
// K-step: issue stage(t+1) -> ds_read+MFMA on buf[t] (64*NI/4 MFMA cluster)
//         -> vmcnt(0) -> ONE barrier. Load latency hides under the MFMA
//         phase instead of being exposed in a barrier convoy (the 128-tile
//         2-barrier structure was stuck at ~430cy overhead per 155cy of
//         MFMA; rounds 1-2 proved micro-changes inside it are null).
// LDS chunk map: row r, chunk q holds global chunk q^(r&7) (b128 reads
// <=2-way bank aliased = free).
// MODE 0 (NI=4): E=exp(scale[n]/(dist+0.1)) -> swizzled 256x256 LDS tile ->
//                coalesced 16B global stores; row sums atomic into denom.
// MODE 3 (NI=2): bf16 store of c into partial slice z.
template<int MODE, int NI>
__global__ __launch_bounds__(512, 2)
void gemm256(const unsigned short* __restrict__ A,
             const unsigned short* __restrict__ B,
             void* __restrict__ Cv,
             int M, int N, int K, int KC,
             const float* __restrict__ aux0,
             const float* __restrict__ aux1,
             const float* __restrict__ aux2,
             float* __restrict__ aux3)
{
  constexpr int BN  = 64 * NI;
  constexpr int NA  = 4;              // A 16B-chunks per thread per stage
  constexpr int NB  = NI;
  constexpr int ASZ = 256 * 64;       // shorts per A slot (32 KB)
  constexpr int BSZ = BN * 64;        // shorts per B slot
  constexpr int SLOT = ASZ + BSZ;
  __shared__ unsigned short smem[2 * SLOT];   // MODE0: 128 KB, MODE3: 96 KB

  const int tid  = threadIdx.x;
  const int lane = tid & 63;
  const int wv   = tid >> 6;
  const int l16  = lane & 15;
  const int quad = lane >> 4;
  const int wm   = (wv >> 2) * 128;         // 2 m-waves
  const int wn   = (wv & 3) * (16 * NI);    // 4 n-waves

  int xt, yt, zt;
  const int lin = blockIdx.x;
  const int xcd = lin & 7;
  if (MODE == 0) {                  // 512 blocks: XCD owns 2-wide n-band x 32 m
    const int i = lin >> 3;         // 0..63
    xt = xcd * 2 + (i & 1);
    yt = i >> 1;
    zt = 0;
  } else {                          // 256 blocks: XCD owns 4 m-tiles x (4e x 2z)
    const int i = lin >> 3;         // 0..31
    yt = xcd * 4 + (i & 3);
    const int combo = i >> 2;       // 0..7
    xt = combo & 3;
    zt = combo >> 2;
  }
  const int n0   = xt * BN;
  const int m0   = yt * 256;
  const int kbeg = zt * KC;

  f32x4 acc[8][NI];
#pragma unroll
  for (int i = 0; i < 8; ++i)
#pragma unroll
    for (int j = 0; j < NI; ++j) {
      f32x4 z = {0.f, 0.f, 0.f, 0.f};
      acc[i][j] = z;
    }

  // staging: LDS chunk c holds global chunk (c&7)^((c>>3)&7) of row c>>3
  const unsigned short* gA[NA]; int lA[NA];
  const unsigned short* gB[NB]; int lB[NB];
#pragma unroll
  for (int i = 0; i < NA; ++i) {
    const int c = tid + i * 512;
    const int row = c >> 3, col = ((c & 7) ^ (row & 7)) * 8;
    gA[i] = A + (size_t)(m0 + row) * K + col + kbeg;
    lA[i] = c * 8;
  }
#pragma unroll
  for (int i = 0; i < NB; ++i) {
    const int c = tid + i * 512;
    const int row = c >> 3, col = ((c & 7) ^ (row & 7)) * 8;
    gB[i] = B + (size_t)(n0 + row) * K + col + kbeg;
    lB[i] = c * 8;
  }

  auto issue = [&](int st, int kc) {
    unsigned short* S = smem + st * SLOT;
#pragma unroll
    for (int i = 0; i < NA; ++i) gl_lds16(gA[i] + kc, &S[lA[i]]);
#pragma unroll
    for (int i = 0; i < NB; ++i) gl_lds16(gB[i] + kc, &S[ASZ + lB[i]]);
  };

  const int nk = KC >> 6;   // BK = 64
  issue(0, 0);
  __builtin_amdgcn_s_waitcnt(0x0F70);       // vmcnt(0): slot0 landed
  __builtin_amdgcn_s_barrier();

  int cur = 0;
  for (int it = 0; it < nk; ++it) {
    if (it + 1 < nk) issue(cur ^ 1, (it + 1) << 6);   // prefetch under compute
    const unsigned short* As = smem + cur * SLOT;
    const unsigned short* Bs = As + ASZ;
    __builtin_amdgcn_s_setprio(1);
#pragma unroll
    for (int ks = 0; ks < 2; ++ks) {
      bf16x8 af[8], bfr[NI];
#pragma unroll
      for (int mi = 0; mi < 8; ++mi) {
        const int r = wm + mi * 16 + l16;
        af[mi] = *(const bf16x8*)&As[r * 64 + (((ks * 4 + quad) ^ (r & 7)) * 8)];
      }
#pragma unroll
      for (int ni = 0; ni < NI; ++ni) {
        const int r = wn + ni * 16 + l16;
        bfr[ni] = *(const bf16x8*)&Bs[r * 64 + (((ks * 4 + quad) ^ (r & 7)) * 8)];
      }
#pragma unroll
      for (int mi = 0; mi < 8; ++mi)
#pragma unroll
        for (int ni = 0; ni < NI; ++ni)
          acc[mi][ni] = MFMA(af[mi], bfr[ni], acc[mi][ni], 0, 0, 0);
    }
    __builtin_amdgcn_s_setprio(0);
    __builtin_amdgcn_s_waitcnt(0x0F70);     // my stage for t+1 landed
    __builtin_amdgcn_s_barrier();           // reads of cur done + next visible
    cur ^= 1;
  }

  // ---- epilogue ----
  if constexpr (MODE == 0) {
    // NI==4: 256x256 E-tile. exp into swizzled LDS, row-sum atomics,
    // then coalesced 16B global stores.
    float p2v[4], scv[4];
#pragma unroll
    for (int ni = 0; ni < 4; ++ni) {
      const int n = n0 + wn + ni * 16 + l16;
      p2v[ni] = aux1[n];
      scv[ni] = aux2[n] * 1.44269504088896f;   // fold log2(e)
    }
    __syncthreads();                            // done with K-loop LDS
    unsigned short* Es = smem;                  // 256 x 256, chunk-XOR swizzled
#pragma unroll
    for (int mi = 0; mi < 8; ++mi) {
#pragma unroll
      for (int r = 0; r < 4; ++r) {
        const int rowL = wm + mi * 16 + quad * 4 + r;
        const float rowa = aux0[m0 + rowL];
        float s = 0.f;
#pragma unroll
        for (int ni = 0; ni < 4; ++ni) {
          const int col = wn + ni * 16 + l16;
          const float v = acc[mi][ni][r];
          float sq   = fmaxf(rowa - 2.0f * v + p2v[ni], 0.0f);
          float dist = __builtin_amdgcn_sqrtf(sq);
          float e    = __builtin_amdgcn_exp2f(scv[ni] * __builtin_amdgcn_rcpf(dist + 0.1f));
          const int ch  = col >> 3;
          const int swz = (ch & 24) | ((ch ^ rowL) & 7);
          Es[rowL * 256 + swz * 8 + (col & 7)] = f2bf(e);
          s += e;                                // unrounded sum (rel err ~3e-5)
        }
        s += __shfl_down(s, 8);
        s += __shfl_down(s, 4);
        s += __shfl_down(s, 2);
        s += __shfl_down(s, 1);
        if (l16 == 0) unsafeAtomicAdd(&aux3[m0 + rowL], s);
      }
    }
    __syncthreads();
    unsigned short* Eg = (unsigned short*)Cv;
#pragma unroll
    for (int j = 0; j < 16; ++j) {              // 256 rows x 32 chunks
      const int cid = j * 512 + tid;
      const int row = cid >> 5, ch = cid & 31;
      const int swz = (ch & 24) | ((ch ^ row) & 7);
      bf16x8 v = *(const bf16x8*)&Es[row * 256 + swz * 8];
      *(bf16x8*)&Eg[(size_t)(m0 + row) * N + n0 + ch * 8] = v;
    }
  } else {
    unsigned short* Pz = (unsigned short*)Cv + (size_t)zt * (size_t)M * N;
#pragma unroll
    for (int mi = 0; mi < 8; ++mi) {
#pragma unroll
      for (int r = 0; r < 4; ++r) {
        const int m = m0 + wm + mi * 16 + quad * 4 + r;
#pragma unroll
        for (int ni = 0; ni < NI; ++ni) {
          const int n = n0 + wn + ni * 16 + l16;
          Pz[(size_t)m * N + n] = f2bf(acc[mi][ni][r]);
        }
      }
    }
  }
}

// ================= 128-tile GEMM (round-0 proven) for the small GEMMs =====
// MODE 2: bf16 store of c. 2-barrier double-buffered global_load_lds loop.
template<int MODE, int SWZ, int WM, int WN>
__global__ __launch_bounds__(WM* WN * 64)
void gemm_bt(const unsigned short* __restrict__ A,
             const unsigned short* __restrict__ B,
             void* __restrict__ Cv,
             int M, int N, int K, int KC,
             const float* __restrict__ aux0,
             const float* __restrict__ aux1,
             const float* __restrict__ aux2,
             float* __restrict__ aux3)
{
  constexpr int THREADS = WM * WN * 64;
  constexpr int BMt = WM * 64, BNt = WN * 64;
  constexpr int NA = BMt * 8 / THREADS;
  constexpr int NB = BNt * 8 / THREADS;
  constexpr int L  = NA + NB;
  constexpr int ASZ = BMt * 64, BSZ = BNt * 64;

  __shared__ unsigned short smem[2 * (ASZ + BSZ)];
  unsigned short* As = smem;
  unsigned short* Bs = smem + 2 * ASZ;

  const int tid  = threadIdx.x;
  const int lane = tid & 63;
  const int wv   = tid >> 6;
  const int wm   = (wv / WN) * 64;
  const int wn   = (wv % WN) * 64;
  const int l16  = lane & 15;
  const int quad = lane >> 4;

  const int xt = blockIdx.x, yt = blockIdx.y;
  const int n0 = xt * BNt;
  const int m0 = yt * BMt;

  f32x4 acc[4][4];
#pragma unroll
  for (int i = 0; i < 4; ++i)
#pragma unroll
    for (int j = 0; j < 4; ++j) {
      f32x4 z = {0.f, 0.f, 0.f, 0.f};
      acc[i][j] = z;
    }

  const unsigned short* gA[NA]; int lA[NA];
  const unsigned short* gB[NB]; int lB[NB];
#pragma unroll
  for (int i = 0; i < NA; ++i) {
    const int c = tid + i * THREADS;
    const int row = c >> 3, col = ((c & 7) ^ (row & 7)) * 8;
    gA[i] = A + (size_t)(m0 + row) * K + col;
    lA[i] = c * 8;
  }
#pragma unroll
  for (int i = 0; i < NB; ++i) {
    const int c = tid + i * THREADS;
    const int row = c >> 3, col = ((c & 7) ^ (row & 7)) * 8;
    gB[i] = B + (size_t)(n0 + row) * K + col;
    lB[i] = c * 8;
  }

  auto issue = [&](int st, int kc) {
#pragma unroll
    for (int i = 0; i < NA; ++i) gl_lds16(gA[i] + kc, &As[st * ASZ + lA[i]]);
#pragma unroll
    for (int i = 0; i < NB; ++i) gl_lds16(gB[i] + kc, &Bs[st * BSZ + lB[i]]);
  };

  const int nk = KC >> 6;
  issue(0, 0);

  int cur = 0;
  for (int it = 0; it < nk; ++it) {
    __builtin_amdgcn_s_barrier();
    if (it + 1 < nk) {
      issue(cur ^ 1, (it + 1) << 6);
      __builtin_amdgcn_s_waitcnt(0x0F70 | L);
    } else {
      __builtin_amdgcn_s_waitcnt(0x0F70);
    }
    __builtin_amdgcn_s_barrier();

#pragma unroll
    for (int ks = 0; ks < 2; ++ks) {
      bf16x8 af[4], bfr[4];
#pragma unroll
      for (int mi = 0; mi < 4; ++mi) {
        const int r = wm + mi * 16 + l16;
        af[mi] = *(const bf16x8*)&As[cur * ASZ + r * 64 + (((ks * 4 + quad) ^ (r & 7)) * 8)];
      }
#pragma unroll
      for (int ni = 0; ni < 4; ++ni) {
        const int r = wn + ni * 16 + l16;
        bfr[ni] = *(const bf16x8*)&Bs[cur * BSZ + r * 64 + (((ks * 4 + quad) ^ (r & 7)) * 8)];
      }
#pragma unroll
      for (int mi = 0; mi < 4; ++mi)
#pragma unroll
        for (int ni = 0; ni < 4; ++ni)
          acc[mi][ni] = MFMA(af[mi], bfr[ni], acc[mi][ni], 0, 0, 0);
    }
    cur ^= 1;
  }

  unsigned short* Pz = (unsigned short*)Cv;
#pragma unroll
  for (int mi = 0; mi < 4; ++mi) {
#pragma unroll
    for (int r = 0; r < 4; ++r) {
      const int m = m0 + wm + mi * 16 + quad * 4 + r;
#pragma unroll
      for (int ni = 0; ni < 4; ++ni) {
        const int n = n0 + wn + ni * 16 + l16;
        Pz[(size_t)m * N + n] = f2bf(acc[mi][ni][r]);
      }
    }
  }
  (void)aux0; (void)aux1; (void)aux2; (void)aux3;
}

// ===== prep_all: all conversions/norms/bias in ONE launch (3456 blocks) =====
// [0,2048): x rows -> xb,x2,denom=0 ; [2048,3072): p rows -> pb,p2 ;
// [3072,3328): wv,wo -> bf16 (straight) ; [3328,3456): bias2
__global__ void prep_all(const float* __restrict__ x, const float* __restrict__ positions,
                         const float* __restrict__ w_v, const float* __restrict__ w_o,
                         const float* __restrict__ b_v, const float* __restrict__ b_o,
                         unsigned short* __restrict__ xb, unsigned short* __restrict__ pb,
                         unsigned short* __restrict__ wvb, unsigned short* __restrict__ wob,
                         float* __restrict__ x2, float* __restrict__ p2,
                         float* __restrict__ bias2, float* __restrict__ denom)
{
  const int b = blockIdx.x;
  const int tid = threadIdx.x;
  const int lane = tid & 63;
  const int wv = tid >> 6;

  if (b < 3072) {
    const bool isx = (b < 2048);
    const int r = (isx ? b : b - 2048) * 4 + wv;
    const float* X = isx ? x : positions;
    unsigned short* Xb = isx ? xb : pb;
    const float4* row = (const float4*)(X + (size_t)r * 512);
    const float4 a = row[lane];
    const float4 c = row[lane + 64];
    ushort4 ua, uc;
    ua.x = f2bf(a.x); ua.y = f2bf(a.y); ua.z = f2bf(a.z); ua.w = f2bf(a.w);
    uc.x = f2bf(c.x); uc.y = f2bf(c.y); uc.z = f2bf(c.z); uc.w = f2bf(c.w);
    ushort4* orow = (ushort4*)(Xb + (size_t)r * 512);
    orow[lane] = ua;
    orow[lane + 64] = uc;
    float s = a.x*a.x + a.y*a.y + a.z*a.z + a.w*a.w
            + c.x*c.x + c.y*c.y + c.z*c.z + c.w*c.w;
#pragma unroll
    for (int off = 32; off > 0; off >>= 1) s += __shfl_down(s, off, 64);
    if (lane == 0) {
      if (isx) { x2[r] = s; denom[r] = 0.f; }
      else     { p2[r] = s; }
    }
  } else if (b < 3328) {
    const int i = (b - 3072) * 256 + tid;   // 65536 float4 each
    float4 a = ((const float4*)w_v)[i];
    float4 c = ((const float4*)w_o)[i];
    ushort4 ua, uc;
    ua.x = f2bf(a.x); ua.y = f2bf(a.y); ua.z = f2bf(a.z); ua.w = f2bf(a.w);
    uc.x = f2bf(c.x); uc.y = f2bf(c.y); uc.z = f2bf(c.z); uc.w = f2bf(c.w);
    ((ushort4*)wvb)[i] = ua;
    ((ushort4*)wob)[i] = uc;
  } else {
    const int e = (b - 3328) * 4 + wv;
    float s = 0.f;
#pragma unroll
    for (int j = 0; j < 8; ++j)
      s += w_o[(size_t)e * 512 + lane + j * 64] * b_v[lane + j * 64];
#pragma unroll
    for (int off = 32; off > 0; off >>= 1) s += __shfl_down(s, off, 64);
    if (lane == 0) bias2[e] = b_o[e] + s;   // softmax rows sum to 1
  }
}

// out[m,e] = (P0[m,e] + P1[m,e]) / denom[m] + bias2[e]   (P bf16, out fp32)
__global__ void reduce_out(const unsigned short* __restrict__ P,
                           const float* __restrict__ denom,
                           const float* __restrict__ bias2,
                           float* __restrict__ out) {
  const int i = blockIdx.x * 256 + threadIdx.x;   // 1,048,576 float4s
  const int m = i >> 7;
  const float rd = 1.0f / denom[m];
  const float4 b4 = ((const float4*)bias2)[i & 127];
  const ushort4 p0 = ((const ushort4*)P)[i];
  const ushort4 p1 = ((const ushort4*)P)[i + 1048576];
  float4 o;
  o.x = (bf2f(p0.x) + bf2f(p1.x)) * rd + b4.x;
  o.y = (bf2f(p0.y) + bf2f(p1.y)) * rd + b4.y;
  o.z = (bf2f(p0.z) + bf2f(p1.z)) * rd + b4.z;
  o.w = (bf2f(p0.w) + bf2f(p1.w)) * rd + b4.w;
  ((float4*)out)[i] = o;
}

extern "C" void kernel_launch(void* const* d_in, const int* in_sizes, int n_in,
                              void* d_out, int out_size, void* d_ws, size_t ws_size,
                              hipStream_t stream) {
  const float* x         = (const float*)d_in[0];
  const float* positions = (const float*)d_in[1];
  const float* scale     = (const float*)d_in[2];
  const float* w_v       = (const float*)d_in[3];
  const float* b_v       = (const float*)d_in[4];
  const float* w_o       = (const float*)d_in[5];
  const float* b_o       = (const float*)d_in[6];
  float* out = (float*)d_out;

  const int M = 8192, N = 4096, D = 512;

  char* base = (char*)d_ws;
  unsigned short* Eb    = (unsigned short*)(base + 0);          // 64 MB [MODE-0 .. MODE-3]
  unsigned short* val   = (unsigned short*)(base + 0);          // 4 MB, parks in Eb [val-GEMM .. v2T-GEMM]
  unsigned short* v2T   = (unsigned short*)(base + 67108864);   // 4 MB
  float*          denom = (float*)(base + 71303168);            // 32 KB
  float*          x2    = (float*)(base + 71335936);            // 32 KB
  float*          p2    = (float*)(base + 71368704);            // 16 KB
  float*          bias2 = (float*)(base + 71385088);            // 2 KB
  char* base2 = base + 71387136;
  unsigned short* part  = (unsigned short*)base2;               // 16 MB [MODE-3 .. reduce]
  unsigned short* xb    = (unsigned short*)base2;               // 8 MB  [prep .. MODE-0]
  unsigned short* pb    = (unsigned short*)(base2 + 8388608);   // 4 MB  [prep .. MODE-0]
  unsigned short* wvb   = (unsigned short*)(base2 + 12582912);  // 0.5 MB [prep .. val-GEMM]
  unsigned short* wo_b  = (unsigned short*)(base2 + 13107200);  // 0.5 MB [prep .. v2T-GEMM]

  // all prep in one launch
  prep_all<<<3456, 256, 0, stream>>>(x, positions, w_v, w_o, b_v, b_o,
                                     xb, pb, wvb, wo_b, x2, p2, bias2, denom);

  // val[n,d] = sum_k p[n,k] wv[d,k]
  gemm_bt<2, 0, 2, 2><<<dim3(4, 32), 256, 0, stream>>>(
      pb, wvb, val, 4096, 512, 512, 512, nullptr, nullptr, nullptr, nullptr);

  // v2T[e,n] = sum_d wo[e,d] val[n,d]
  gemm_bt<2, 0, 2, 2><<<dim3(32, 4), 256, 0, stream>>>(
      wo_b, val, v2T, 512, 4096, 512, 512, nullptr, nullptr, nullptr, nullptr);

  // E[m,n] = exp(scale[n]/(dist+0.1)); denom[m] += row sums   (256^2 tile)
  gemm256<0, 4><<<512, 512, 0, stream>>>(
      xb, pb, Eb, M, N, D, D, x2, p2, scale, denom);

  // part[z][m,e] = sum_{n in half z} E[m,n] v2T[e,n]   (256x128 tile, z=2)
  gemm256<3, 2><<<256, 512, 0, stream>>>(
      Eb, v2T, part, M, 512, N, N / 2, nullptr, nullptr, nullptr, nullptr);

  // out = (part0 + part1)/denom + bias2
  reduce_out<<<4096, 256, 0, stream>>>(part, denom, bias2, out);
}